// Round 10
// baseline (243.068 us; speedup 1.0000x reference)
//
#include <hip/hip_runtime.h>
#include <hip/hip_bf16.h>

// Problem constants (fixed by the reference).
#define B_  2
#define N_  2048
#define D_  512
#define H_  8
#define HD_ 64
#define NSPLIT_ 2
#define KRANGE_ (N_ / NSPLIT_)   // 1024

typedef float  f4  __attribute__((ext_vector_type(4)));
typedef int    i4  __attribute__((ext_vector_type(4)));
typedef short  bf16x8 __attribute__((ext_vector_type(8)));   // 8 bf16 (4 VGPRs)
typedef float  f32x4  __attribute__((ext_vector_type(4)));   // MFMA C/D frag
typedef unsigned short u16x8 __attribute__((ext_vector_type(8)));

// float -> bf16 (round to nearest even).
static __device__ __forceinline__ unsigned short f2bf(float f) {
    union { float f; unsigned int u; } v; v.f = f;
    unsigned int r = v.u + 0x7fffu + ((v.u >> 16) & 1u);
    return (unsigned short)(r >> 16);
}

// ---------------------------------------------------------------------------
// Prep: convert x (2M f32) and Wq/Wk/Wv/Wo (4 x 256K f32) to bf16.
// ---------------------------------------------------------------------------
__global__ __launch_bounds__(256) void prep_kernel(
    const float* __restrict__ x,
    const float* __restrict__ Wq, const float* __restrict__ Wk,
    const float* __restrict__ Wv, const float* __restrict__ Wo,
    unsigned short* __restrict__ xh, unsigned short* __restrict__ WhAll)
{
    const size_t e = ((size_t)blockIdx.x * 256 + threadIdx.x) * 8;
    const float* src;
    unsigned short* dst;
    if (e < 2097152) {            // x
        src = x + e;  dst = xh + e;
    } else {
        const size_t e2 = e - 2097152;
        const int wi = (int)(e2 >> 18);          // 262144 = 2^18 per W
        const size_t off = e2 & 262143;
        const float* Ws = (wi == 0) ? Wq : (wi == 1) ? Wk : (wi == 2) ? Wv : Wo;
        src = Ws + off;  dst = WhAll + (size_t)wi * 262144 + off;
    }
    f4 a = *(const f4*)src;
    f4 b = *(const f4*)(src + 4);
    u16x8 o;
    #pragma unroll
    for (int j = 0; j < 4; ++j) { o[j] = f2bf(a[j]); o[j + 4] = f2bf(b[j]); }
    *(u16x8*)dst = o;
}

// ---------------------------------------------------------------------------
// bf16 MFMA GEMM (validated round 7): C[r,c] = sum_k Ah[r,k]*Wh[c,k] + bias[c]
// Tile 128x128, BK=64, 4 waves 2x2, wave tile 64x64 of mfma_f32_16x16x32_bf16.
// ---------------------------------------------------------------------------
template <int OUT_MODE>
__device__ __forceinline__ void mfma_gemm_body(
    const unsigned short* __restrict__ Ah, const unsigned short* __restrict__ Wh,
    const float* __restrict__ bias, float* __restrict__ outf,
    unsigned short* __restrict__ outh, int r0, int c0)
{
    __shared__ unsigned short Asm[128][72];
    __shared__ unsigned short Bsm[128][72];

    const int tid  = threadIdx.x;
    const int lane = tid & 63;
    const int w    = tid >> 6;
    const int wr   = w >> 1, wc = w & 1;
    const int l15  = lane & 15, lhi = lane >> 4;

    f32x4 acc[4][4];
    #pragma unroll
    for (int mi = 0; mi < 4; ++mi)
        #pragma unroll
        for (int ni = 0; ni < 4; ++ni)
            acc[mi][ni] = (f32x4){0.f, 0.f, 0.f, 0.f};

    for (int kt = 0; kt < 512; kt += 64) {
        __syncthreads();
        #pragma unroll
        for (int i = 0; i < 4; ++i) {
            const int v   = tid + i * 256;
            const int row = v >> 3;
            const int c8  = (v & 7) * 8;
            *(u16x8*)&Asm[row][c8] =
                *(const u16x8*)&Ah[(size_t)(r0 + row) * 512 + kt + c8];
            *(u16x8*)&Bsm[row][c8] =
                *(const u16x8*)&Wh[(size_t)(c0 + row) * 512 + kt + c8];
        }
        __syncthreads();

        #pragma unroll
        for (int ks = 0; ks < 2; ++ks) {
            bf16x8 a[4], bb[4];
            #pragma unroll
            for (int mi = 0; mi < 4; ++mi)
                a[mi] = *(const bf16x8*)&Asm[wr * 64 + mi * 16 + l15][ks * 32 + lhi * 8];
            #pragma unroll
            for (int ni = 0; ni < 4; ++ni)
                bb[ni] = *(const bf16x8*)&Bsm[wc * 64 + ni * 16 + l15][ks * 32 + lhi * 8];
            #pragma unroll
            for (int mi = 0; mi < 4; ++mi)
                #pragma unroll
                for (int ni = 0; ni < 4; ++ni)
                    acc[mi][ni] = __builtin_amdgcn_mfma_f32_16x16x32_bf16(
                        a[mi], bb[ni], acc[mi][ni], 0, 0, 0);
        }
    }

    #pragma unroll
    for (int ni = 0; ni < 4; ++ni) {
        const int c = c0 + wc * 64 + ni * 16 + l15;
        const float bias_c = bias[c];
        #pragma unroll
        for (int mi = 0; mi < 4; ++mi) {
            #pragma unroll
            for (int reg = 0; reg < 4; ++reg) {
                const int r = r0 + wr * 64 + mi * 16 + lhi * 4 + reg;
                const float vv = acc[mi][ni][reg] + bias_c;
                if (OUT_MODE == 0) {
                    outf[(size_t)r * 512 + c] = vv;
                } else {
                    const int bbn = r >> 11, n = r & (N_ - 1);
                    const int h = c >> 6, hd = c & 63;
                    outh[(((size_t)(bbn * H_ + h)) * N_ + n) * HD_ + hd] = f2bf(vv);
                }
            }
        }
    }
}

__global__ __launch_bounds__(256) void qkv_mfma_kernel(
    const unsigned short* __restrict__ xh, const unsigned short* __restrict__ WhAll,
    const float* __restrict__ bq, const float* __restrict__ bk,
    const float* __restrict__ bv,
    unsigned short* __restrict__ Qh, unsigned short* __restrict__ Kh,
    unsigned short* __restrict__ Vh)
{
    const int z = blockIdx.z;
    const unsigned short* Wh = WhAll + (size_t)z * 262144;
    const float* bias = (z == 0) ? bq : (z == 1) ? bk : bv;
    unsigned short* dst = (z == 0) ? Qh : (z == 1) ? Kh : Vh;
    mfma_gemm_body<1>(xh, Wh, bias, nullptr, dst,
                      blockIdx.y * 128, blockIdx.x * 128);
}

__global__ __launch_bounds__(256) void wo_mfma_kernel(
    const unsigned short* __restrict__ ctxh, const unsigned short* __restrict__ WhAll,
    const float* __restrict__ bo, float* __restrict__ y1)
{
    mfma_gemm_body<0>(ctxh, WhAll + 3 * 262144, bo, y1, nullptr,
                      blockIdx.y * 128, blockIdx.x * 128);
}

// ---------------------------------------------------------------------------
// Split-K MFMA masked flash attention.  Per-tile math identical to the
// validated round-7 kernel; blockIdx.z selects K-range [z*1024,(z+1)*1024).
// Epilogue stores UNNORMALIZED partial O (f32) + per-row (m, l).
// Grid (32, 16, 2) = 1024 blocks -> 4 blocks/CU -> 16 waves/CU (was 8).
// ---------------------------------------------------------------------------
__global__ __launch_bounds__(256) void attn_split_kernel(
    const unsigned short* __restrict__ Q, const unsigned short* __restrict__ K,
    const unsigned short* __restrict__ V, const int* __restrict__ adj,
    float* __restrict__ Opart, float* __restrict__ ML)
{
    __shared__ unsigned short K_lds[64][72];
    __shared__ unsigned short Vt_lds[64][72];     // transposed: [dv][k]
    __shared__ unsigned short P_lds[4][16][72];   // per-wave P tile

    const int tid  = threadIdx.x;
    const int lane = tid & 63;
    const int w    = tid >> 6;
    const int l15  = lane & 15, lhi = lane >> 4;
    const int bh = blockIdx.y;
    const int b  = bh >> 3;
    const int q0 = blockIdx.x * 64;
    const int split = blockIdx.z;
    const int kbeg  = split * KRANGE_;

    const unsigned short* Qbh = Q + (size_t)bh * N_ * HD_;
    const unsigned short* Kbh = K + (size_t)bh * N_ * HD_;
    const unsigned short* Vbh = V + (size_t)bh * N_ * HD_;
    const int* adjb = adj + (size_t)b * N_ * N_;

    const int qrow = q0 + w * 16 + l15;
    bf16x8 aq0 = *(const bf16x8*)&Qbh[(size_t)qrow * HD_ + lhi * 8];
    bf16x8 aq1 = *(const bf16x8*)&Qbh[(size_t)qrow * HD_ + 32 + lhi * 8];

    const int qrow_base = q0 + w * 16 + lhi * 4;

    f32x4 acc[4];
    #pragma unroll
    for (int t = 0; t < 4; ++t) acc[t] = (f32x4){0.f, 0.f, 0.f, 0.f};
    float m_r[4], l_r[4];
    const float NEG_INF = -__builtin_inff();
    #pragma unroll
    for (int r = 0; r < 4; ++r) { m_r[r] = NEG_INF; l_r[r] = 0.0f; }

    const float scale = 0.125f;

    int adjc[4][4], adjn[4][4];
    #pragma unroll
    for (int r = 0; r < 4; ++r)
        #pragma unroll
        for (int kt = 0; kt < 4; ++kt)
            adjc[r][kt] = adjb[(size_t)(qrow_base + r) * N_ + kbeg + kt * 16 + l15];

    for (int kc = kbeg; kc < kbeg + KRANGE_; kc += 64) {
        __syncthreads();

        {   // Stage K tile [64][64] -> K_lds.
            const int k  = tid & 63;
            const int c2 = tid >> 6;
            u16x8 k0 = *(const u16x8*)&Kbh[(size_t)(kc + k) * HD_ + c2 * 8];
            u16x8 k1 = *(const u16x8*)&Kbh[(size_t)(kc + k) * HD_ + (c2 + 4) * 8];
            *(u16x8*)&K_lds[k][c2 * 8]       = k0;
            *(u16x8*)&K_lds[k][(c2 + 4) * 8] = k1;
        }
        {   // Stage V tile transposed -> Vt_lds.
            const int k2  = (tid & 31) * 2;
            const int dvb = (tid >> 5) * 8;
            u16x8 v0 = *(const u16x8*)&Vbh[(size_t)(kc + k2) * HD_ + dvb];
            u16x8 v1 = *(const u16x8*)&Vbh[(size_t)(kc + k2 + 1) * HD_ + dvb];
            #pragma unroll
            for (int i = 0; i < 8; ++i) {
                unsigned int pair = (unsigned int)(unsigned short)v0[i] |
                                    ((unsigned int)(unsigned short)v1[i] << 16);
                *(unsigned int*)&Vt_lds[dvb + i][k2] = pair;
            }
        }

        // Prefetch next tile's adjacency (wraps within this split's range).
        const int kcn = kbeg + ((kc - kbeg + 64) & (KRANGE_ - 1));
        #pragma unroll
        for (int r = 0; r < 4; ++r)
            #pragma unroll
            for (int kt = 0; kt < 4; ++kt)
                adjn[r][kt] = adjb[(size_t)(qrow_base + r) * N_ + kcn + kt * 16 + l15];

        __syncthreads();

        f32x4 s[4];
        #pragma unroll
        for (int kt = 0; kt < 4; ++kt) {
            bf16x8 bk0 = *(const bf16x8*)&K_lds[kt * 16 + l15][lhi * 8];
            bf16x8 bk1 = *(const bf16x8*)&K_lds[kt * 16 + l15][32 + lhi * 8];
            f32x4 z = {0.f, 0.f, 0.f, 0.f};
            z = __builtin_amdgcn_mfma_f32_16x16x32_bf16(aq0, bk0, z, 0, 0, 0);
            s[kt] = __builtin_amdgcn_mfma_f32_16x16x32_bf16(aq1, bk1, z, 0, 0, 0);
        }

        #pragma unroll
        for (int r = 0; r < 4; ++r) {
            float sm[4];
            #pragma unroll
            for (int kt = 0; kt < 4; ++kt)
                sm[kt] = adjc[r][kt] ? s[kt][r] * scale : NEG_INF;
            float mx = fmaxf(fmaxf(sm[0], sm[1]), fmaxf(sm[2], sm[3]));
            #pragma unroll
            for (int off = 1; off < 16; off <<= 1)
                mx = fmaxf(mx, __shfl_xor(mx, off));
            const float mnew = fmaxf(m_r[r], mx);
            float fac, p[4];
            if (mnew == NEG_INF) {
                fac = 1.0f;
                p[0] = p[1] = p[2] = p[3] = 0.0f;
            } else {
                fac = __expf(m_r[r] - mnew);
                #pragma unroll
                for (int kt = 0; kt < 4; ++kt)
                    p[kt] = __expf(sm[kt] - mnew);
            }
            m_r[r] = mnew;
            float rs = p[0] + p[1] + p[2] + p[3];
            #pragma unroll
            for (int off = 1; off < 16; off <<= 1)
                rs += __shfl_xor(rs, off);
            l_r[r] = l_r[r] * fac + rs;
            #pragma unroll
            for (int t = 0; t < 4; ++t) acc[t][r] *= fac;
            #pragma unroll
            for (int kt = 0; kt < 4; ++kt)
                P_lds[w][lhi * 4 + r][kt * 16 + l15] = f2bf(p[kt]);
        }

        #pragma unroll
        for (int ks = 0; ks < 2; ++ks) {
            bf16x8 ap = *(const bf16x8*)&P_lds[w][l15][ks * 32 + lhi * 8];
            #pragma unroll
            for (int dvt = 0; dvt < 4; ++dvt) {
                bf16x8 bv = *(const bf16x8*)&Vt_lds[dvt * 16 + l15][ks * 32 + lhi * 8];
                acc[dvt] = __builtin_amdgcn_mfma_f32_16x16x32_bf16(ap, bv, acc[dvt], 0, 0, 0);
            }
        }

        #pragma unroll
        for (int r = 0; r < 4; ++r)
            #pragma unroll
            for (int kt = 0; kt < 4; ++kt)
                adjc[r][kt] = adjn[r][kt];
    }

    // Epilogue: store UNNORMALIZED partial O + (m, l) per row.
    float* Osplit = Opart + (size_t)split * (16 * 2048 * 64);
    #pragma unroll
    for (int r = 0; r < 4; ++r) {
        const int q = qrow_base + r;
        #pragma unroll
        for (int dvt = 0; dvt < 4; ++dvt)
            Osplit[((size_t)bh * 2048 + q) * 64 + dvt * 16 + l15] = acc[dvt][r];
        if (l15 == 0) {
            float2* ml = (float2*)ML;
            ml[(size_t)split * 32768 + bh * 2048 + q] =
                make_float2(m_r[r], l_r[r]);
        }
    }
}

// ---------------------------------------------------------------------------
// Combine the NSPLIT partials: ctx = (sum_i e^(m_i-M) O_i) / (sum_i e^(m_i-M) l_i)
// One wave per (bh, q) row, lane = hd.  4 rows per block.
// ---------------------------------------------------------------------------
__global__ __launch_bounds__(256) void combine_kernel(
    const float* __restrict__ Opart, const float* __restrict__ ML,
    unsigned short* __restrict__ ctxh)
{
    const int row  = blockIdx.x * 4 + (threadIdx.x >> 6);   // bh*2048 + q
    const int lane = threadIdx.x & 63;
    const float NEG_INF = -__builtin_inff();

    const float2 ml0 = ((const float2*)ML)[row];
    const float2 ml1 = ((const float2*)ML)[32768 + row];
    const float M  = fmaxf(ml0.x, ml1.x);
    const float s0 = (ml0.x == NEG_INF) ? 0.0f : __expf(ml0.x - M);
    const float s1 = (ml1.x == NEG_INF) ? 0.0f : __expf(ml1.x - M);
    const float L  = ml0.y * s0 + ml1.y * s1;
    const float inv = (L > 0.0f) ? 1.0f / L : 0.0f;

    const float o0 = Opart[(size_t)row * 64 + lane];
    const float o1 = Opart[(size_t)(16 * 2048 * 64) + (size_t)row * 64 + lane];
    const float o  = (o0 * s0 + o1 * s1) * inv;

    const int bh = row >> 11, q = row & 2047;
    const int b = bh >> 3, hh = bh & 7;
    ctxh[((size_t)(b * 2048 + q)) * 512 + hh * 64 + lane] = f2bf(o);
}

// ---------------------------------------------------------------------------
// Residual + LayerNorm: out = LN(x + y1) * gamma + beta.  One wave per row.
// ---------------------------------------------------------------------------
__global__ __launch_bounds__(64) void ln_kernel(
    const float* __restrict__ x, const float* __restrict__ y1,
    const float* __restrict__ gamma, const float* __restrict__ beta,
    float* __restrict__ out)
{
    const int row = blockIdx.x;
    const int tid = threadIdx.x;
    const size_t base = (size_t)row * 512 + tid * 8;

    f4 v0 = *(const f4*)&x[base]     + *(const f4*)&y1[base];
    f4 v1 = *(const f4*)&x[base + 4] + *(const f4*)&y1[base + 4];

    float s = v0[0] + v0[1] + v0[2] + v0[3] + v1[0] + v1[1] + v1[2] + v1[3];
    #pragma unroll
    for (int off = 1; off < 64; off <<= 1) s += __shfl_xor(s, off);
    const float mu = s * (1.0f / 512.0f);

    float d2 = 0.0f;
    #pragma unroll
    for (int j = 0; j < 4; ++j) {
        const float a = v0[j] - mu, bq = v1[j] - mu;
        d2 += a * a + bq * bq;
    }
    #pragma unroll
    for (int off = 1; off < 64; off <<= 1) d2 += __shfl_xor(d2, off);
    const float rstd = rsqrtf(d2 * (1.0f / 512.0f) + 1e-5f);

    f4 g0 = *(const f4*)&gamma[tid * 8];
    f4 g1 = *(const f4*)&gamma[tid * 8 + 4];
    f4 be0 = *(const f4*)&beta[tid * 8];
    f4 be1 = *(const f4*)&beta[tid * 8 + 4];
    f4 o0, o1;
    #pragma unroll
    for (int j = 0; j < 4; ++j) {
        o0[j] = (v0[j] - mu) * rstd * g0[j] + be0[j];
        o1[j] = (v1[j] - mu) * rstd * g1[j] + be1[j];
    }
    *(f4*)&out[base]     = o0;
    *(f4*)&out[base + 4] = o1;
}

// ---------------------------------------------------------------------------
extern "C" void kernel_launch(void* const* d_in, const int* in_sizes, int n_in,
                              void* d_out, int out_size, void* d_ws, size_t ws_size,
                              hipStream_t stream)
{
    const float* x     = (const float*)d_in[0];
    const int*   adj   = (const int*)  d_in[1];
    const float* Wq    = (const float*)d_in[2];
    const float* bq    = (const float*)d_in[3];
    const float* Wk    = (const float*)d_in[4];
    const float* bk    = (const float*)d_in[5];
    const float* Wv    = (const float*)d_in[6];
    const float* bv    = (const float*)d_in[7];
    const float* Wo    = (const float*)d_in[8];
    const float* bo    = (const float*)d_in[9];
    const float* gamma = (const float*)d_in[10];
    const float* beta  = (const float*)d_in[11];
    float* out = (float*)d_out;

    const size_t elems = (size_t)B_ * N_ * D_;   // 2,097,152
    unsigned short* Qh    = (unsigned short*)d_ws;   // bf16 segments (4 MB each):
    unsigned short* Kh    = Qh   + elems;
    unsigned short* Vh    = Kh   + elems;
    unsigned short* ctxh  = Vh   + elems;
    unsigned short* xh    = ctxh + elems;
    unsigned short* WhAll = xh   + elems;            // 4 x 262144 (2 MB)
    float* Opart = (float*)(WhAll + 4 * 262144);     // 2 x 8 MB f32 partials
    float* ML    = Opart + 2 * (16 * 2048 * 64);     // 2 x 32768 float2 (512 KB)
    float* y1 = (float*)Qh;    // overlay: Qh/Kh dead after attention

    // 1. Convert x + weights to bf16.
    prep_kernel<<<1536, 256, 0, stream>>>(x, Wq, Wk, Wv, Wo, xh, WhAll);

    // 2. QKV projections (bf16 MFMA).
    qkv_mfma_kernel<<<dim3(4, 32, 3), 256, 0, stream>>>(
        xh, WhAll, bq, bk, bv, Qh, Kh, Vh);

    // 3. Split-K masked flash attention (2x occupancy) + combine.
    attn_split_kernel<<<dim3(N_ / 64, B_ * H_, NSPLIT_), 256, 0, stream>>>(
        Qh, Kh, Vh, adj, Opart, ML);
    combine_kernel<<<(16 * 2048) / 4, 256, 0, stream>>>(Opart, ML, ctxh);

    // 4. Output projection (bf16 MFMA, fp32 out).
    wo_mfma_kernel<<<dim3(4, 32), 256, 0, stream>>>(ctxh, WhAll, bo, y1);

    // 5. Residual + LayerNorm.
    ln_kernel<<<B_ * N_, 64, 0, stream>>>(x, y1, gamma, beta, out);
}

// Round 11
// 225.603 us; speedup vs baseline: 1.0774x; 1.0774x over previous
//
#include <hip/hip_runtime.h>
#include <hip/hip_bf16.h>

// Problem constants (fixed by the reference).
#define B_  2
#define N_  2048
#define D_  512
#define H_  8
#define HD_ 64

typedef float  f4  __attribute__((ext_vector_type(4)));
typedef int    i4  __attribute__((ext_vector_type(4)));
typedef short  bf16x8 __attribute__((ext_vector_type(8)));   // 8 bf16 (4 VGPRs)
typedef float  f32x4  __attribute__((ext_vector_type(4)));   // MFMA C/D frag
typedef unsigned short u16x8 __attribute__((ext_vector_type(8)));
typedef unsigned short u16x4 __attribute__((ext_vector_type(4)));

// float -> bf16 (round to nearest even).
static __device__ __forceinline__ unsigned short f2bf(float f) {
    union { float f; unsigned int u; } v; v.f = f;
    unsigned int r = v.u + 0x7fffu + ((v.u >> 16) & 1u);
    return (unsigned short)(r >> 16);
}

// ---------------------------------------------------------------------------
// Prep: convert x (2M f32) and Wq/Wk/Wv/Wo (4 x 256K f32) to bf16.
// ---------------------------------------------------------------------------
__global__ __launch_bounds__(256) void prep_kernel(
    const float* __restrict__ x,
    const float* __restrict__ Wq, const float* __restrict__ Wk,
    const float* __restrict__ Wv, const float* __restrict__ Wo,
    unsigned short* __restrict__ xh, unsigned short* __restrict__ WhAll)
{
    const size_t e = ((size_t)blockIdx.x * 256 + threadIdx.x) * 8;
    const float* src;
    unsigned short* dst;
    if (e < 2097152) {            // x
        src = x + e;  dst = xh + e;
    } else {
        const size_t e2 = e - 2097152;
        const int wi = (int)(e2 >> 18);          // 262144 = 2^18 per W
        const size_t off = e2 & 262143;
        const float* Ws = (wi == 0) ? Wq : (wi == 1) ? Wk : (wi == 2) ? Wv : Wo;
        src = Ws + off;  dst = WhAll + (size_t)wi * 262144 + off;
    }
    f4 a = *(const f4*)src;
    f4 b = *(const f4*)(src + 4);
    u16x8 o;
    #pragma unroll
    for (int j = 0; j < 4; ++j) { o[j] = f2bf(a[j]); o[j + 4] = f2bf(b[j]); }
    *(u16x8*)dst = o;
}

// ---------------------------------------------------------------------------
// bf16 MFMA GEMM (validated round 7): C[r,c] = sum_k Ah[r,k]*Wh[c,k] + bias[c]
// Tile 128x128, BK=64, 4 waves 2x2, wave tile 64x64 of mfma_f32_16x16x32_bf16.
// ---------------------------------------------------------------------------
template <int OUT_MODE>
__device__ __forceinline__ void mfma_gemm_body(
    const unsigned short* __restrict__ Ah, const unsigned short* __restrict__ Wh,
    const float* __restrict__ bias, float* __restrict__ outf,
    unsigned short* __restrict__ outh, int r0, int c0)
{
    __shared__ unsigned short Asm[128][72];
    __shared__ unsigned short Bsm[128][72];

    const int tid  = threadIdx.x;
    const int lane = tid & 63;
    const int w    = tid >> 6;
    const int wr   = w >> 1, wc = w & 1;
    const int l15  = lane & 15, lhi = lane >> 4;

    f32x4 acc[4][4];
    #pragma unroll
    for (int mi = 0; mi < 4; ++mi)
        #pragma unroll
        for (int ni = 0; ni < 4; ++ni)
            acc[mi][ni] = (f32x4){0.f, 0.f, 0.f, 0.f};

    for (int kt = 0; kt < 512; kt += 64) {
        __syncthreads();
        #pragma unroll
        for (int i = 0; i < 4; ++i) {
            const int v   = tid + i * 256;
            const int row = v >> 3;
            const int c8  = (v & 7) * 8;
            *(u16x8*)&Asm[row][c8] =
                *(const u16x8*)&Ah[(size_t)(r0 + row) * 512 + kt + c8];
            *(u16x8*)&Bsm[row][c8] =
                *(const u16x8*)&Wh[(size_t)(c0 + row) * 512 + kt + c8];
        }
        __syncthreads();

        #pragma unroll
        for (int ks = 0; ks < 2; ++ks) {
            bf16x8 a[4], bb[4];
            #pragma unroll
            for (int mi = 0; mi < 4; ++mi)
                a[mi] = *(const bf16x8*)&Asm[wr * 64 + mi * 16 + l15][ks * 32 + lhi * 8];
            #pragma unroll
            for (int ni = 0; ni < 4; ++ni)
                bb[ni] = *(const bf16x8*)&Bsm[wc * 64 + ni * 16 + l15][ks * 32 + lhi * 8];
            #pragma unroll
            for (int mi = 0; mi < 4; ++mi)
                #pragma unroll
                for (int ni = 0; ni < 4; ++ni)
                    acc[mi][ni] = __builtin_amdgcn_mfma_f32_16x16x32_bf16(
                        a[mi], bb[ni], acc[mi][ni], 0, 0, 0);
        }
    }

    #pragma unroll
    for (int ni = 0; ni < 4; ++ni) {
        const int c = c0 + wc * 64 + ni * 16 + l15;
        const float bias_c = bias[c];
        #pragma unroll
        for (int mi = 0; mi < 4; ++mi) {
            #pragma unroll
            for (int reg = 0; reg < 4; ++reg) {
                const int r = r0 + wr * 64 + mi * 16 + lhi * 4 + reg;
                const float vv = acc[mi][ni][reg] + bias_c;
                if (OUT_MODE == 0) {
                    outf[(size_t)r * 512 + c] = vv;
                } else {
                    const int bbn = r >> 11, n = r & (N_ - 1);
                    const int h = c >> 6, hd = c & 63;
                    outh[(((size_t)(bbn * H_ + h)) * N_ + n) * HD_ + hd] = f2bf(vv);
                }
            }
        }
    }
}

__global__ __launch_bounds__(256) void qkv_mfma_kernel(
    const unsigned short* __restrict__ xh, const unsigned short* __restrict__ WhAll,
    const float* __restrict__ bq, const float* __restrict__ bk,
    const float* __restrict__ bv,
    unsigned short* __restrict__ Qh, unsigned short* __restrict__ Kh,
    unsigned short* __restrict__ Vh)
{
    const int z = blockIdx.z;
    const unsigned short* Wh = WhAll + (size_t)z * 262144;
    const float* bias = (z == 0) ? bq : (z == 1) ? bk : bv;
    unsigned short* dst = (z == 0) ? Qh : (z == 1) ? Kh : Vh;
    mfma_gemm_body<1>(xh, Wh, bias, nullptr, dst,
                      blockIdx.y * 128, blockIdx.x * 128);
}

__global__ __launch_bounds__(256) void wo_mfma_kernel(
    const unsigned short* __restrict__ ctxh, const unsigned short* __restrict__ WhAll,
    const float* __restrict__ bo, float* __restrict__ y1)
{
    mfma_gemm_body<0>(ctxh, WhAll + 3 * 262144, bo, y1, nullptr,
                      blockIdx.y * 128, blockIdx.x * 128);
}

// ---------------------------------------------------------------------------
// MFMA masked flash attention, SWAPPED QK^T for in-register softmax.
// S^T = mfma(K_frag, Q_frag): q = lane&15, k = (lane>>4)*4 + reg.
// Each lane owns ALL 64 k-scores of one q-row per tile (16 regs) ->
// row max/sum = in-register + 2 shfl_xor (lanes sharing q differ in bits 4-5).
// Rescale factors / final 1/l redistributed via per-wave LDS (within-wave).
// Staging, Vt layout, PV step identical to the round-7 validated kernel.
// ---------------------------------------------------------------------------
__global__ __launch_bounds__(256) void attn_kernel(
    const unsigned short* __restrict__ Q, const unsigned short* __restrict__ K,
    const unsigned short* __restrict__ V, const int* __restrict__ adj,
    unsigned short* __restrict__ ctxh)
{
    __shared__ unsigned short K_lds[64][72];
    __shared__ unsigned short Vt_lds[64][72];     // transposed: [dv][k]
    __shared__ unsigned short P_lds[4][16][72];   // per-wave P tile [q][k]
    __shared__ float fac_lds[4][16];              // per-wave q -> factor bcast

    const int tid  = threadIdx.x;
    const int lane = tid & 63;
    const int w    = tid >> 6;
    const int l15  = lane & 15, lhi = lane >> 4;
    const int bh = blockIdx.y;
    const int b  = bh >> 3;
    const int hh = bh & 7;
    const int q0 = blockIdx.x * 64;

    const unsigned short* Qbh = Q + (size_t)bh * N_ * HD_;
    const unsigned short* Kbh = K + (size_t)bh * N_ * HD_;
    const unsigned short* Vbh = V + (size_t)bh * N_ * HD_;
    const int* adjb = adj + (size_t)b * N_ * N_;

    // Q fragment: this lane's q-row for the softmax path is q0+w*16+l15.
    const int qrow = q0 + w * 16 + l15;
    bf16x8 aq0 = *(const bf16x8*)&Qbh[(size_t)qrow * HD_ + lhi * 8];
    bf16x8 aq1 = *(const bf16x8*)&Qbh[(size_t)qrow * HD_ + 32 + lhi * 8];

    const int qrow_base = q0 + w * 16 + lhi * 4;   // acc C-tile rows (PV output)

    f32x4 acc[4];      // ctx [16q x 64dv]: acc[dvt][r] = ctx[qrow_base+r][dvt*16+l15]
    #pragma unroll
    for (int t = 0; t < 4; ++t) acc[t] = (f32x4){0.f, 0.f, 0.f, 0.f};
    float m_q = -__builtin_inff();   // online max for THIS lane's q-row
    float l_q = 0.0f;
    const float NEG_INF = -__builtin_inff();
    const float scale = 0.125f;

    // Adjacency: lane's q-row, k contiguous in lhi*4..+3 per 16-k subtile.
    i4 adjc[4], adjn[4];
    #pragma unroll
    for (int kt = 0; kt < 4; ++kt)
        adjc[kt] = *(const i4*)&adjb[(size_t)qrow * N_ + kt * 16 + lhi * 4];

    for (int kc = 0; kc < N_; kc += 64) {
        __syncthreads();   // previous tile's LDS reads complete

        {   // Stage K tile [64][64] -> K_lds.
            const int k  = tid & 63;
            const int c2 = tid >> 6;
            u16x8 k0 = *(const u16x8*)&Kbh[(size_t)(kc + k) * HD_ + c2 * 8];
            u16x8 k1 = *(const u16x8*)&Kbh[(size_t)(kc + k) * HD_ + (c2 + 4) * 8];
            *(u16x8*)&K_lds[k][c2 * 8]       = k0;
            *(u16x8*)&K_lds[k][(c2 + 4) * 8] = k1;
        }
        {   // Stage V tile transposed -> Vt_lds.
            const int k2  = (tid & 31) * 2;
            const int dvb = (tid >> 5) * 8;
            u16x8 v0 = *(const u16x8*)&Vbh[(size_t)(kc + k2) * HD_ + dvb];
            u16x8 v1 = *(const u16x8*)&Vbh[(size_t)(kc + k2 + 1) * HD_ + dvb];
            #pragma unroll
            for (int i = 0; i < 8; ++i) {
                unsigned int pair = (unsigned int)(unsigned short)v0[i] |
                                    ((unsigned int)(unsigned short)v1[i] << 16);
                *(unsigned int*)&Vt_lds[dvb + i][k2] = pair;
            }
        }

        // Prefetch next tile's adjacency (wrapped; unused on last iter).
        const int kcn = (kc + 64) & (N_ - 1);
        #pragma unroll
        for (int kt = 0; kt < 4; ++kt)
            adjn[kt] = *(const i4*)&adjb[(size_t)qrow * N_ + kcn + kt * 16 + lhi * 4];

        __syncthreads();   // staging visible

        // ---- S^T = K.Q^T : 4 k-subtiles; D: q=l15, k=lhi*4+reg.
        f32x4 s[4];
        #pragma unroll
        for (int kt = 0; kt < 4; ++kt) {
            bf16x8 bk0 = *(const bf16x8*)&K_lds[kt * 16 + l15][lhi * 8];
            bf16x8 bk1 = *(const bf16x8*)&K_lds[kt * 16 + l15][32 + lhi * 8];
            f32x4 z = {0.f, 0.f, 0.f, 0.f};
            z = __builtin_amdgcn_mfma_f32_16x16x32_bf16(bk0, aq0, z, 0, 0, 0);
            s[kt] = __builtin_amdgcn_mfma_f32_16x16x32_bf16(bk1, aq1, z, 0, 0, 0);
        }

        // ---- In-register online softmax (one q-row per lane, 16 scores).
        float sm[16];
        #pragma unroll
        for (int kt = 0; kt < 4; ++kt)
            #pragma unroll
            for (int r = 0; r < 4; ++r)
                sm[kt * 4 + r] = adjc[kt][r] ? s[kt][r] * scale : NEG_INF;

        float mx = sm[0];
        #pragma unroll
        for (int i = 1; i < 16; ++i) mx = fmaxf(mx, sm[i]);
        mx = fmaxf(mx, __shfl_xor(mx, 16));
        mx = fmaxf(mx, __shfl_xor(mx, 32));

        const float mnew = fmaxf(m_q, mx);
        float fac, p[16];
        if (mnew == NEG_INF) {           // q-row fully masked so far
            fac = 1.0f;
            #pragma unroll
            for (int i = 0; i < 16; ++i) p[i] = 0.0f;
        } else {
            fac = __expf(m_q - mnew);    // m_q = -inf -> 0
            #pragma unroll
            for (int i = 0; i < 16; ++i)
                p[i] = __expf(sm[i] - mnew);   // -inf -> 0
        }
        m_q = mnew;

        float rs = 0.0f;
        #pragma unroll
        for (int i = 0; i < 16; ++i) rs += p[i];
        rs += __shfl_xor(rs, 16);
        rs += __shfl_xor(rs, 32);
        l_q = l_q * fac + rs;

        // ---- Redistribute fac (per q=l15) to acc layout (q=lhi*4+r).
        if (lhi == 0) fac_lds[w][l15] = fac;
        f4 fac4 = *(const f4*)&fac_lds[w][lhi * 4];
        #pragma unroll
        for (int t = 0; t < 4; ++t)
            #pragma unroll
            for (int r = 0; r < 4; ++r)
                acc[t][r] *= fac4[r];

        // ---- P -> bf16 -> P_lds[q][k] (k-contiguous b64 writes).
        #pragma unroll
        for (int kt = 0; kt < 4; ++kt) {
            u16x4 pw;
            #pragma unroll
            for (int r = 0; r < 4; ++r) pw[r] = f2bf(p[kt * 4 + r]);
            *(u16x4*)&P_lds[w][l15][kt * 16 + lhi * 4] = pw;
        }

        // ---- ctx += P.V  (A-frag from P_lds, B-frag from Vt_lds).
        #pragma unroll
        for (int ks = 0; ks < 2; ++ks) {
            bf16x8 ap = *(const bf16x8*)&P_lds[w][l15][ks * 32 + lhi * 8];
            #pragma unroll
            for (int dvt = 0; dvt < 4; ++dvt) {
                bf16x8 bv = *(const bf16x8*)&Vt_lds[dvt * 16 + l15][ks * 32 + lhi * 8];
                acc[dvt] = __builtin_amdgcn_mfma_f32_16x16x32_bf16(ap, bv, acc[dvt], 0, 0, 0);
            }
        }

        #pragma unroll
        for (int kt = 0; kt < 4; ++kt) adjc[kt] = adjn[kt];
    }

    // ---- Epilogue: redistribute final l, normalize, store bf16 ctx.
    if (lhi == 0) fac_lds[w][l15] = l_q;
    f4 lv = *(const f4*)&fac_lds[w][lhi * 4];
    #pragma unroll
    for (int r = 0; r < 4; ++r) {
        const int q = qrow_base + r;
        const float inv = (lv[r] > 0.0f) ? 1.0f / lv[r] : 0.0f;
        #pragma unroll
        for (int dvt = 0; dvt < 4; ++dvt)
            ctxh[((size_t)(b * N_ + q)) * D_ + hh * HD_ + dvt * 16 + l15] =
                f2bf(acc[dvt][r] * inv);
    }
}

// ---------------------------------------------------------------------------
// Residual + LayerNorm: out = LN(x + y1) * gamma + beta.  One wave per row.
// ---------------------------------------------------------------------------
__global__ __launch_bounds__(64) void ln_kernel(
    const float* __restrict__ x, const float* __restrict__ y1,
    const float* __restrict__ gamma, const float* __restrict__ beta,
    float* __restrict__ out)
{
    const int row = blockIdx.x;
    const int tid = threadIdx.x;
    const size_t base = (size_t)row * 512 + tid * 8;

    f4 v0 = *(const f4*)&x[base]     + *(const f4*)&y1[base];
    f4 v1 = *(const f4*)&x[base + 4] + *(const f4*)&y1[base + 4];

    float s = v0[0] + v0[1] + v0[2] + v0[3] + v1[0] + v1[1] + v1[2] + v1[3];
    #pragma unroll
    for (int off = 1; off < 64; off <<= 1) s += __shfl_xor(s, off);
    const float mu = s * (1.0f / 512.0f);

    float d2 = 0.0f;
    #pragma unroll
    for (int j = 0; j < 4; ++j) {
        const float a = v0[j] - mu, bq = v1[j] - mu;
        d2 += a * a + bq * bq;
    }
    #pragma unroll
    for (int off = 1; off < 64; off <<= 1) d2 += __shfl_xor(d2, off);
    const float rstd = rsqrtf(d2 * (1.0f / 512.0f) + 1e-5f);

    f4 g0 = *(const f4*)&gamma[tid * 8];
    f4 g1 = *(const f4*)&gamma[tid * 8 + 4];
    f4 be0 = *(const f4*)&beta[tid * 8];
    f4 be1 = *(const f4*)&beta[tid * 8 + 4];
    f4 o0, o1;
    #pragma unroll
    for (int j = 0; j < 4; ++j) {
        o0[j] = (v0[j] - mu) * rstd * g0[j] + be0[j];
        o1[j] = (v1[j] - mu) * rstd * g1[j] + be1[j];
    }
    *(f4*)&out[base]     = o0;
    *(f4*)&out[base + 4] = o1;
}

// ---------------------------------------------------------------------------
extern "C" void kernel_launch(void* const* d_in, const int* in_sizes, int n_in,
                              void* d_out, int out_size, void* d_ws, size_t ws_size,
                              hipStream_t stream)
{
    const float* x     = (const float*)d_in[0];
    const int*   adj   = (const int*)  d_in[1];
    const float* Wq    = (const float*)d_in[2];
    const float* bq    = (const float*)d_in[3];
    const float* Wk    = (const float*)d_in[4];
    const float* bk    = (const float*)d_in[5];
    const float* Wv    = (const float*)d_in[6];
    const float* bv    = (const float*)d_in[7];
    const float* Wo    = (const float*)d_in[8];
    const float* bo    = (const float*)d_in[9];
    const float* gamma = (const float*)d_in[10];
    const float* beta  = (const float*)d_in[11];
    float* out = (float*)d_out;

    const size_t elems = (size_t)B_ * N_ * D_;   // 2,097,152
    unsigned short* Qh    = (unsigned short*)d_ws;   // bf16 segments (4 MB each):
    unsigned short* Kh    = Qh   + elems;
    unsigned short* Vh    = Kh   + elems;
    unsigned short* ctxh  = Vh   + elems;
    unsigned short* xh    = ctxh + elems;
    unsigned short* WhAll = xh   + elems;            // 4 x 262144 (2 MB)
    float* y1 = (float*)Qh;    // overlay: Qh/Kh dead after attention

    // 1. Convert x + weights to bf16.
    prep_kernel<<<1536, 256, 0, stream>>>(x, Wq, Wk, Wv, Wo, xh, WhAll);

    // 2. QKV projections (bf16 MFMA).
    qkv_mfma_kernel<<<dim3(4, 32, 3), 256, 0, stream>>>(
        xh, WhAll, bq, bk, bv, Qh, Kh, Vh);

    // 3. Masked flash attention (swapped-QK^T in-register softmax).
    attn_kernel<<<dim3(N_ / 64, B_ * H_), 256, 0, stream>>>(Qh, Kh, Vh, adj, ctxh);

    // 4. Output projection (bf16 MFMA, fp32 out).
    wo_mfma_kernel<<<dim3(4, 32), 256, 0, stream>>>(ctxh, WhAll, bo, y1);

    // 5. Residual + LayerNorm.
    ln_kernel<<<B_ * N_, 64, 0, stream>>>(x, y1, gamma, beta, out);
}

// Round 14
// 212.091 us; speedup vs baseline: 1.1461x; 1.0637x over previous
//
#include <hip/hip_runtime.h>
#include <hip/hip_bf16.h>

// Problem constants (fixed by the reference).
#define B_  2
#define N_  2048
#define D_  512
#define H_  8
#define HD_ 64

typedef float  f4  __attribute__((ext_vector_type(4)));
typedef int    i4  __attribute__((ext_vector_type(4)));
typedef short  bf16x8 __attribute__((ext_vector_type(8)));   // 8 bf16 (4 VGPRs)
typedef float  f32x4  __attribute__((ext_vector_type(4)));   // MFMA C/D frag
typedef unsigned short u16x8 __attribute__((ext_vector_type(8)));
typedef unsigned short u16x4 __attribute__((ext_vector_type(4)));

// float -> bf16 (round to nearest even).
static __device__ __forceinline__ unsigned short f2bf(float f) {
    union { float f; unsigned int u; } v; v.f = f;
    unsigned int r = v.u + 0x7fffu + ((v.u >> 16) & 1u);
    return (unsigned short)(r >> 16);
}

// ---------------------------------------------------------------------------
// Prep: convert x (2M f32) and Wq/Wk/Wv/Wo (4 x 256K f32) to bf16.
// ---------------------------------------------------------------------------
__global__ __launch_bounds__(256) void prep_kernel(
    const float* __restrict__ x,
    const float* __restrict__ Wq, const float* __restrict__ Wk,
    const float* __restrict__ Wv, const float* __restrict__ Wo,
    unsigned short* __restrict__ xh, unsigned short* __restrict__ WhAll)
{
    const size_t e = ((size_t)blockIdx.x * 256 + threadIdx.x) * 8;
    const float* src;
    unsigned short* dst;
    if (e < 2097152) {            // x
        src = x + e;  dst = xh + e;
    } else {
        const size_t e2 = e - 2097152;
        const int wi = (int)(e2 >> 18);          // 262144 = 2^18 per W
        const size_t off = e2 & 262143;
        const float* Ws = (wi == 0) ? Wq : (wi == 1) ? Wk : (wi == 2) ? Wv : Wo;
        src = Ws + off;  dst = WhAll + (size_t)wi * 262144 + off;
    }
    f4 a = *(const f4*)src;
    f4 b = *(const f4*)(src + 4);
    u16x8 o;
    #pragma unroll
    for (int j = 0; j < 4; ++j) { o[j] = f2bf(a[j]); o[j + 4] = f2bf(b[j]); }
    *(u16x8*)dst = o;
}

// ---------------------------------------------------------------------------
// bf16 MFMA GEMM (validated round 7): C[r,c] = sum_k Ah[r,k]*Wh[c,k] + bias[c]
// Tile 128x128, BK=64, 4 waves 2x2, wave tile 64x64 of mfma_f32_16x16x32_bf16.
// ---------------------------------------------------------------------------
template <int OUT_MODE>
__device__ __forceinline__ void mfma_gemm_body(
    const unsigned short* __restrict__ Ah, const unsigned short* __restrict__ Wh,
    const float* __restrict__ bias, float* __restrict__ outf,
    unsigned short* __restrict__ outh, int r0, int c0)
{
    __shared__ unsigned short Asm[128][72];
    __shared__ unsigned short Bsm[128][72];

    const int tid  = threadIdx.x;
    const int lane = tid & 63;
    const int w    = tid >> 6;
    const int wr   = w >> 1, wc = w & 1;
    const int l15  = lane & 15, lhi = lane >> 4;

    f32x4 acc[4][4];
    #pragma unroll
    for (int mi = 0; mi < 4; ++mi)
        #pragma unroll
        for (int ni = 0; ni < 4; ++ni)
            acc[mi][ni] = (f32x4){0.f, 0.f, 0.f, 0.f};

    for (int kt = 0; kt < 512; kt += 64) {
        __syncthreads();
        #pragma unroll
        for (int i = 0; i < 4; ++i) {
            const int v   = tid + i * 256;
            const int row = v >> 3;
            const int c8  = (v & 7) * 8;
            *(u16x8*)&Asm[row][c8] =
                *(const u16x8*)&Ah[(size_t)(r0 + row) * 512 + kt + c8];
            *(u16x8*)&Bsm[row][c8] =
                *(const u16x8*)&Wh[(size_t)(c0 + row) * 512 + kt + c8];
        }
        __syncthreads();

        #pragma unroll
        for (int ks = 0; ks < 2; ++ks) {
            bf16x8 a[4], bb[4];
            #pragma unroll
            for (int mi = 0; mi < 4; ++mi)
                a[mi] = *(const bf16x8*)&Asm[wr * 64 + mi * 16 + l15][ks * 32 + lhi * 8];
            #pragma unroll
            for (int ni = 0; ni < 4; ++ni)
                bb[ni] = *(const bf16x8*)&Bsm[wc * 64 + ni * 16 + l15][ks * 32 + lhi * 8];
            #pragma unroll
            for (int mi = 0; mi < 4; ++mi)
                #pragma unroll
                for (int ni = 0; ni < 4; ++ni)
                    acc[mi][ni] = __builtin_amdgcn_mfma_f32_16x16x32_bf16(
                        a[mi], bb[ni], acc[mi][ni], 0, 0, 0);
        }
    }

    #pragma unroll
    for (int ni = 0; ni < 4; ++ni) {
        const int c = c0 + wc * 64 + ni * 16 + l15;
        const float bias_c = bias[c];
        #pragma unroll
        for (int mi = 0; mi < 4; ++mi) {
            #pragma unroll
            for (int reg = 0; reg < 4; ++reg) {
                const int r = r0 + wr * 64 + mi * 16 + lhi * 4 + reg;
                const float vv = acc[mi][ni][reg] + bias_c;
                if (OUT_MODE == 0) {
                    outf[(size_t)r * 512 + c] = vv;
                } else {
                    const int bbn = r >> 11, n = r & (N_ - 1);
                    const int h = c >> 6, hd = c & 63;
                    outh[(((size_t)(bbn * H_ + h)) * N_ + n) * HD_ + hd] = f2bf(vv);
                }
            }
        }
    }
}

__global__ __launch_bounds__(256) void qkv_mfma_kernel(
    const unsigned short* __restrict__ xh, const unsigned short* __restrict__ WhAll,
    const float* __restrict__ bq, const float* __restrict__ bk,
    const float* __restrict__ bv,
    unsigned short* __restrict__ Qh, unsigned short* __restrict__ Kh,
    unsigned short* __restrict__ Vh)
{
    const int z = blockIdx.z;
    const unsigned short* Wh = WhAll + (size_t)z * 262144;
    const float* bias = (z == 0) ? bq : (z == 1) ? bk : bv;
    unsigned short* dst = (z == 0) ? Qh : (z == 1) ? Kh : Vh;
    mfma_gemm_body<1>(xh, Wh, bias, nullptr, dst,
                      blockIdx.y * 128, blockIdx.x * 128);
}

__global__ __launch_bounds__(256) void wo_mfma_kernel(
    const unsigned short* __restrict__ ctxh, const unsigned short* __restrict__ WhAll,
    const float* __restrict__ bo, float* __restrict__ y1)
{
    mfma_gemm_body<0>(ctxh, WhAll + 3 * 262144, bo, y1, nullptr,
                      blockIdx.y * 128, blockIdx.x * 128);
}

// ---------------------------------------------------------------------------
// MFMA masked flash attention: swapped QK^T in-register softmax (validated
// round 11) + double-buffered async staging (T14/2-phase):
//   issue next-tile global loads -> compute tile t -> ds_write buf^1 -> 1 barrier
// The vmcnt drain lands AFTER ~1500 cycles of compute; barriers 2 -> 1 per tile.
// ---------------------------------------------------------------------------
__global__ __launch_bounds__(256) void attn_kernel(
    const unsigned short* __restrict__ Q, const unsigned short* __restrict__ K,
    const unsigned short* __restrict__ V, const int* __restrict__ adj,
    unsigned short* __restrict__ ctxh)
{
    __shared__ unsigned short K_lds[2][64][72];
    __shared__ unsigned short Vt_lds[2][64][72];  // transposed: [dv][k]
    __shared__ unsigned short P_lds[4][16][72];   // per-wave P tile [q][k]
    __shared__ float fac_lds[4][16];              // per-wave q -> factor bcast

    const int tid  = threadIdx.x;
    const int lane = tid & 63;
    const int w    = tid >> 6;
    const int l15  = lane & 15, lhi = lane >> 4;
    const int bh = blockIdx.y;
    const int b  = bh >> 3;
    const int hh = bh & 7;
    const int q0 = blockIdx.x * 64;

    const unsigned short* Qbh = Q + (size_t)bh * N_ * HD_;
    const unsigned short* Kbh = K + (size_t)bh * N_ * HD_;
    const unsigned short* Vbh = V + (size_t)bh * N_ * HD_;
    const int* adjb = adj + (size_t)b * N_ * N_;

    // Per-thread staging coordinates (same mapping as validated kernel).
    const int sk  = tid & 63;          // K row within tile
    const int sc2 = tid >> 6;          // 0..3 (d-chunk)
    const int sv_k2  = (tid & 31) * 2; // V row pair
    const int sv_dvb = (tid >> 5) * 8; // V d-chunk

    // Q fragment: this lane's q-row for the softmax path is q0+w*16+l15.
    const int qrow = q0 + w * 16 + l15;
    bf16x8 aq0 = *(const bf16x8*)&Qbh[(size_t)qrow * HD_ + lhi * 8];
    bf16x8 aq1 = *(const bf16x8*)&Qbh[(size_t)qrow * HD_ + 32 + lhi * 8];

    const int qrow_base = q0 + w * 16 + lhi * 4;   // acc C-tile rows (PV output)

    f32x4 acc[4];
    #pragma unroll
    for (int t = 0; t < 4; ++t) acc[t] = (f32x4){0.f, 0.f, 0.f, 0.f};
    float m_q = -__builtin_inff();
    float l_q = 0.0f;
    const float NEG_INF = -__builtin_inff();
    const float scale = 0.125f;

    // ---- Prologue: stage tile 0 into buffer 0.
    {
        u16x8 k0 = *(const u16x8*)&Kbh[(size_t)sk * HD_ + sc2 * 8];
        u16x8 k1 = *(const u16x8*)&Kbh[(size_t)sk * HD_ + (sc2 + 4) * 8];
        *(u16x8*)&K_lds[0][sk][sc2 * 8]       = k0;
        *(u16x8*)&K_lds[0][sk][(sc2 + 4) * 8] = k1;
        u16x8 v0 = *(const u16x8*)&Vbh[(size_t)sv_k2 * HD_ + sv_dvb];
        u16x8 v1 = *(const u16x8*)&Vbh[(size_t)(sv_k2 + 1) * HD_ + sv_dvb];
        #pragma unroll
        for (int i = 0; i < 8; ++i) {
            unsigned int pair = (unsigned int)(unsigned short)v0[i] |
                                ((unsigned int)(unsigned short)v1[i] << 16);
            *(unsigned int*)&Vt_lds[0][sv_dvb + i][sv_k2] = pair;
        }
    }
    // Adjacency for tile 0 (lane's q-row, k contiguous in lhi*4..+3).
    i4 adjc[4], adjn[4];
    #pragma unroll
    for (int kt = 0; kt < 4; ++kt)
        adjc[kt] = *(const i4*)&adjb[(size_t)qrow * N_ + kt * 16 + lhi * 4];
    __syncthreads();

    int cur = 0;
    for (int kc = 0; kc < N_; kc += 64) {
        // ---- Issue next tile's loads (latency hides under this tile's compute).
        const int kcn = (kc + 64) & (N_ - 1);   // wraps on last iter (harmless)
        u16x8 nk0 = *(const u16x8*)&Kbh[(size_t)(kcn + sk) * HD_ + sc2 * 8];
        u16x8 nk1 = *(const u16x8*)&Kbh[(size_t)(kcn + sk) * HD_ + (sc2 + 4) * 8];
        u16x8 nv0 = *(const u16x8*)&Vbh[(size_t)(kcn + sv_k2) * HD_ + sv_dvb];
        u16x8 nv1 = *(const u16x8*)&Vbh[(size_t)(kcn + sv_k2 + 1) * HD_ + sv_dvb];
        #pragma unroll
        for (int kt = 0; kt < 4; ++kt)
            adjn[kt] = *(const i4*)&adjb[(size_t)qrow * N_ + kcn + kt * 16 + lhi * 4];

        // ---- S^T = K.Q^T on buf[cur]: D: q=l15, k=lhi*4+reg.
        f32x4 s[4];
        #pragma unroll
        for (int kt = 0; kt < 4; ++kt) {
            bf16x8 bk0 = *(const bf16x8*)&K_lds[cur][kt * 16 + l15][lhi * 8];
            bf16x8 bk1 = *(const bf16x8*)&K_lds[cur][kt * 16 + l15][32 + lhi * 8];
            f32x4 z = {0.f, 0.f, 0.f, 0.f};
            z = __builtin_amdgcn_mfma_f32_16x16x32_bf16(bk0, aq0, z, 0, 0, 0);
            s[kt] = __builtin_amdgcn_mfma_f32_16x16x32_bf16(bk1, aq1, z, 0, 0, 0);
        }

        // ---- In-register online softmax (one q-row per lane, 16 scores).
        float sm[16];
        #pragma unroll
        for (int kt = 0; kt < 4; ++kt)
            #pragma unroll
            for (int r = 0; r < 4; ++r)
                sm[kt * 4 + r] = adjc[kt][r] ? s[kt][r] * scale : NEG_INF;

        float mx = sm[0];
        #pragma unroll
        for (int i = 1; i < 16; ++i) mx = fmaxf(mx, sm[i]);
        mx = fmaxf(mx, __shfl_xor(mx, 16));
        mx = fmaxf(mx, __shfl_xor(mx, 32));

        const float mnew = fmaxf(m_q, mx);
        float fac, p[16];
        if (mnew == NEG_INF) {
            fac = 1.0f;
            #pragma unroll
            for (int i = 0; i < 16; ++i) p[i] = 0.0f;
        } else {
            fac = __expf(m_q - mnew);
            #pragma unroll
            for (int i = 0; i < 16; ++i)
                p[i] = __expf(sm[i] - mnew);
        }
        m_q = mnew;

        float rs = 0.0f;
        #pragma unroll
        for (int i = 0; i < 16; ++i) rs += p[i];
        rs += __shfl_xor(rs, 16);
        rs += __shfl_xor(rs, 32);
        l_q = l_q * fac + rs;

        // ---- Redistribute fac (per q=l15) to acc layout (q=lhi*4+r).
        if (lhi == 0) fac_lds[w][l15] = fac;
        f4 fac4 = *(const f4*)&fac_lds[w][lhi * 4];
        #pragma unroll
        for (int t = 0; t < 4; ++t)
            #pragma unroll
            for (int r = 0; r < 4; ++r)
                acc[t][r] *= fac4[r];

        // ---- P -> bf16 -> P_lds[q][k] (wave-local).
        #pragma unroll
        for (int kt = 0; kt < 4; ++kt) {
            u16x4 pw;
            #pragma unroll
            for (int r = 0; r < 4; ++r) pw[r] = f2bf(p[kt * 4 + r]);
            *(u16x4*)&P_lds[w][l15][kt * 16 + lhi * 4] = pw;
        }

        // ---- ctx += P.V on buf[cur].
        #pragma unroll
        for (int ks = 0; ks < 2; ++ks) {
            bf16x8 ap = *(const bf16x8*)&P_lds[w][l15][ks * 32 + lhi * 8];
            #pragma unroll
            for (int dvt = 0; dvt < 4; ++dvt) {
                bf16x8 bv = *(const bf16x8*)&Vt_lds[cur][dvt * 16 + l15][ks * 32 + lhi * 8];
                acc[dvt] = __builtin_amdgcn_mfma_f32_16x16x32_bf16(ap, bv, acc[dvt], 0, 0, 0);
            }
        }

        // ---- Write staged regs into the other buffer (vmcnt drains here,
        //      after compute) and make visible with ONE barrier.
        const int nxt = cur ^ 1;
        *(u16x8*)&K_lds[nxt][sk][sc2 * 8]       = nk0;
        *(u16x8*)&K_lds[nxt][sk][(sc2 + 4) * 8] = nk1;
        #pragma unroll
        for (int i = 0; i < 8; ++i) {
            unsigned int pair = (unsigned int)(unsigned short)nv0[i] |
                                ((unsigned int)(unsigned short)nv1[i] << 16);
            *(unsigned int*)&Vt_lds[nxt][sv_dvb + i][sv_k2] = pair;
        }
        __syncthreads();
        cur = nxt;

        #pragma unroll
        for (int kt = 0; kt < 4; ++kt) adjc[kt] = adjn[kt];
    }

    // ---- Epilogue: redistribute final l, normalize, store bf16 ctx.
    if (lhi == 0) fac_lds[w][l15] = l_q;
    f4 lv = *(const f4*)&fac_lds[w][lhi * 4];
    #pragma unroll
    for (int r = 0; r < 4; ++r) {
        const int q = qrow_base + r;
        const float inv = (lv[r] > 0.0f) ? 1.0f / lv[r] : 0.0f;
        #pragma unroll
        for (int dvt = 0; dvt < 4; ++dvt)
            ctxh[((size_t)(b * N_ + q)) * D_ + hh * HD_ + dvt * 16 + l15] =
                f2bf(acc[dvt][r] * inv);
    }
}

// ---------------------------------------------------------------------------
// Residual + LayerNorm: out = LN(x + y1) * gamma + beta.  One wave per row.
// ---------------------------------------------------------------------------
__global__ __launch_bounds__(64) void ln_kernel(
    const float* __restrict__ x, const float* __restrict__ y1,
    const float* __restrict__ gamma, const float* __restrict__ beta,
    float* __restrict__ out)
{
    const int row = blockIdx.x;
    const int tid = threadIdx.x;
    const size_t base = (size_t)row * 512 + tid * 8;

    f4 v0 = *(const f4*)&x[base]     + *(const f4*)&y1[base];
    f4 v1 = *(const f4*)&x[base + 4] + *(const f4*)&y1[base + 4];

    float s = v0[0] + v0[1] + v0[2] + v0[3] + v1[0] + v1[1] + v1[2] + v1[3];
    #pragma unroll
    for (int off = 1; off < 64; off <<= 1) s += __shfl_xor(s, off);
    const float mu = s * (1.0f / 512.0f);

    float d2 = 0.0f;
    #pragma unroll
    for (int j = 0; j < 4; ++j) {
        const float a = v0[j] - mu, bq = v1[j] - mu;
        d2 += a * a + bq * bq;
    }
    #pragma unroll
    for (int off = 1; off < 64; off <<= 1) d2 += __shfl_xor(d2, off);
    const float rstd = rsqrtf(d2 * (1.0f / 512.0f) + 1e-5f);

    f4 g0 = *(const f4*)&gamma[tid * 8];
    f4 g1 = *(const f4*)&gamma[tid * 8 + 4];
    f4 be0 = *(const f4*)&beta[tid * 8];
    f4 be1 = *(const f4*)&beta[tid * 8 + 4];
    f4 o0, o1;
    #pragma unroll
    for (int j = 0; j < 4; ++j) {
        o0[j] = (v0[j] - mu) * rstd * g0[j] + be0[j];
        o1[j] = (v1[j] - mu) * rstd * g1[j] + be1[j];
    }
    *(f4*)&out[base]     = o0;
    *(f4*)&out[base + 4] = o1;
}

// ---------------------------------------------------------------------------
extern "C" void kernel_launch(void* const* d_in, const int* in_sizes, int n_in,
                              void* d_out, int out_size, void* d_ws, size_t ws_size,
                              hipStream_t stream)
{
    const float* x     = (const float*)d_in[0];
    const int*   adj   = (const int*)  d_in[1];
    const float* Wq    = (const float*)d_in[2];
    const float* bq    = (const float*)d_in[3];
    const float* Wk    = (const float*)d_in[4];
    const float* bk    = (const float*)d_in[5];
    const float* Wv    = (const float*)d_in[6];
    const float* bv    = (const float*)d_in[7];
    const float* Wo    = (const float*)d_in[8];
    const float* bo    = (const float*)d_in[9];
    const float* gamma = (const float*)d_in[10];
    const float* beta  = (const float*)d_in[11];
    float* out = (float*)d_out;

    const size_t elems = (size_t)B_ * N_ * D_;   // 2,097,152
    unsigned short* Qh    = (unsigned short*)d_ws;   // bf16 segments (4 MB each):
    unsigned short* Kh    = Qh   + elems;
    unsigned short* Vh    = Kh   + elems;
    unsigned short* ctxh  = Vh   + elems;
    unsigned short* xh    = ctxh + elems;
    unsigned short* WhAll = xh   + elems;            // 4 x 262144 (2 MB)
    float* y1 = (float*)Qh;    // overlay: Qh/Kh dead after attention

    // 1. Convert x + weights to bf16.
    prep_kernel<<<1536, 256, 0, stream>>>(x, Wq, Wk, Wv, Wo, xh, WhAll);

    // 2. QKV projections (bf16 MFMA).
    qkv_mfma_kernel<<<dim3(4, 32, 3), 256, 0, stream>>>(
        xh, WhAll, bq, bk, bv, Qh, Kh, Vh);

    // 3. Masked flash attention (in-register softmax + async dbuf staging).
    attn_kernel<<<dim3(N_ / 64, B_ * H_), 256, 0, stream>>>(Qh, Kh, Vh, adj, ctxh);

    // 4. Output projection (bf16 MFMA, fp32 out).
    wo_mfma_kernel<<<dim3(4, 32), 256, 0, stream>>>(ctxh, WhAll, bo, y1);

    // 5. Residual + LayerNorm.
    ln_kernel<<<B_ * N_, 64, 0, stream>>>(x, y1, gamma, beta, out);
}

// Round 15
// 199.471 us; speedup vs baseline: 1.2186x; 1.0633x over previous
//
#include <hip/hip_runtime.h>
#include <hip/hip_bf16.h>

// Problem constants (fixed by the reference).
#define B_  2
#define N_  2048
#define D_  512
#define H_  8
#define HD_ 64

typedef float  f4  __attribute__((ext_vector_type(4)));
typedef int    i4  __attribute__((ext_vector_type(4)));
typedef short  bf16x8 __attribute__((ext_vector_type(8)));   // 8 bf16 (4 VGPRs)
typedef float  f32x4  __attribute__((ext_vector_type(4)));   // MFMA C/D frag
typedef unsigned short u16x8 __attribute__((ext_vector_type(8)));
typedef unsigned short u16x4 __attribute__((ext_vector_type(4)));

// float -> bf16 (round to nearest even).
static __device__ __forceinline__ unsigned short f2bf(float f) {
    union { float f; unsigned int u; } v; v.f = f;
    unsigned int r = v.u + 0x7fffu + ((v.u >> 16) & 1u);
    return (unsigned short)(r >> 16);
}

// ---------------------------------------------------------------------------
// bf16 MFMA GEMM: C[r,c] = sum_k A[r,k]*W[c,k] + bias[c]
// W is read as f32 and converted inline during staging (prep kernel removed;
// same f2bf -> bit-identical to the old prep path).  A is f32 (A_IS_F32=1,
// for x) or bf16 (A_IS_F32=0, for attention ctx).
// Tile 128x128, BK=64, 4 waves 2x2, wave tile 64x64 of mfma_f32_16x16x32_bf16.
// ---------------------------------------------------------------------------
template <int OUT_MODE, int A_IS_F32>
__device__ __forceinline__ void mfma_gemm_body(
    const float* __restrict__ Af, const unsigned short* __restrict__ Ah,
    const float* __restrict__ Wf, const float* __restrict__ bias,
    float* __restrict__ outf, unsigned short* __restrict__ outh,
    int r0, int c0)
{
    __shared__ unsigned short Asm[128][72];
    __shared__ unsigned short Bsm[128][72];

    const int tid  = threadIdx.x;
    const int lane = tid & 63;
    const int w    = tid >> 6;
    const int wr   = w >> 1, wc = w & 1;
    const int l15  = lane & 15, lhi = lane >> 4;

    f32x4 acc[4][4];
    #pragma unroll
    for (int mi = 0; mi < 4; ++mi)
        #pragma unroll
        for (int ni = 0; ni < 4; ++ni)
            acc[mi][ni] = (f32x4){0.f, 0.f, 0.f, 0.f};

    for (int kt = 0; kt < 512; kt += 64) {
        __syncthreads();
        #pragma unroll
        for (int i = 0; i < 4; ++i) {
            const int v   = tid + i * 256;
            const int row = v >> 3;
            const int c8  = (v & 7) * 8;
            if (A_IS_F32) {
                f4 a0 = *(const f4*)&Af[(size_t)(r0 + row) * 512 + kt + c8];
                f4 a1 = *(const f4*)&Af[(size_t)(r0 + row) * 512 + kt + c8 + 4];
                u16x8 oa;
                #pragma unroll
                for (int j = 0; j < 4; ++j) { oa[j] = f2bf(a0[j]); oa[j + 4] = f2bf(a1[j]); }
                *(u16x8*)&Asm[row][c8] = oa;
            } else {
                *(u16x8*)&Asm[row][c8] =
                    *(const u16x8*)&Ah[(size_t)(r0 + row) * 512 + kt + c8];
            }
            f4 w0 = *(const f4*)&Wf[(size_t)(c0 + row) * 512 + kt + c8];
            f4 w1 = *(const f4*)&Wf[(size_t)(c0 + row) * 512 + kt + c8 + 4];
            u16x8 ow;
            #pragma unroll
            for (int j = 0; j < 4; ++j) { ow[j] = f2bf(w0[j]); ow[j + 4] = f2bf(w1[j]); }
            *(u16x8*)&Bsm[row][c8] = ow;
        }
        __syncthreads();

        #pragma unroll
        for (int ks = 0; ks < 2; ++ks) {
            bf16x8 a[4], bb[4];
            #pragma unroll
            for (int mi = 0; mi < 4; ++mi)
                a[mi] = *(const bf16x8*)&Asm[wr * 64 + mi * 16 + l15][ks * 32 + lhi * 8];
            #pragma unroll
            for (int ni = 0; ni < 4; ++ni)
                bb[ni] = *(const bf16x8*)&Bsm[wc * 64 + ni * 16 + l15][ks * 32 + lhi * 8];
            __builtin_amdgcn_s_setprio(1);
            #pragma unroll
            for (int mi = 0; mi < 4; ++mi)
                #pragma unroll
                for (int ni = 0; ni < 4; ++ni)
                    acc[mi][ni] = __builtin_amdgcn_mfma_f32_16x16x32_bf16(
                        a[mi], bb[ni], acc[mi][ni], 0, 0, 0);
            __builtin_amdgcn_s_setprio(0);
        }
    }

    #pragma unroll
    for (int ni = 0; ni < 4; ++ni) {
        const int c = c0 + wc * 64 + ni * 16 + l15;
        const float bias_c = bias[c];
        #pragma unroll
        for (int mi = 0; mi < 4; ++mi) {
            #pragma unroll
            for (int reg = 0; reg < 4; ++reg) {
                const int r = r0 + wr * 64 + mi * 16 + lhi * 4 + reg;
                const float vv = acc[mi][ni][reg] + bias_c;
                if (OUT_MODE == 0) {
                    outf[(size_t)r * 512 + c] = vv;
                } else {
                    const int bbn = r >> 11, n = r & (N_ - 1);
                    const int h = c >> 6, hd = c & 63;
                    outh[(((size_t)(bbn * H_ + h)) * N_ + n) * HD_ + hd] = f2bf(vv);
                }
            }
        }
    }
}

__global__ __launch_bounds__(256) void qkv_mfma_kernel(
    const float* __restrict__ x,
    const float* __restrict__ Wq, const float* __restrict__ Wk,
    const float* __restrict__ Wv,
    const float* __restrict__ bq, const float* __restrict__ bk,
    const float* __restrict__ bv,
    unsigned short* __restrict__ Qh, unsigned short* __restrict__ Kh,
    unsigned short* __restrict__ Vh)
{
    const int z = blockIdx.z;
    const float* Wf = (z == 0) ? Wq : (z == 1) ? Wk : Wv;
    const float* bias = (z == 0) ? bq : (z == 1) ? bk : bv;
    unsigned short* dst = (z == 0) ? Qh : (z == 1) ? Kh : Vh;
    mfma_gemm_body<1, 1>(x, nullptr, Wf, bias, nullptr, dst,
                         blockIdx.y * 128, blockIdx.x * 128);
}

__global__ __launch_bounds__(256) void wo_mfma_kernel(
    const unsigned short* __restrict__ ctxh, const float* __restrict__ Wo,
    const float* __restrict__ bo, float* __restrict__ y1)
{
    mfma_gemm_body<0, 0>(nullptr, ctxh, Wo, bo, y1, nullptr,
                         blockIdx.y * 128, blockIdx.x * 128);
}

// ---------------------------------------------------------------------------
// MFMA masked flash attention: swapped QK^T in-register softmax + async dbuf
// staging (both validated) + NEW: defer-max (T13, THR=8) and setprio (T5).
// defer-max: when the whole wave's row-max growth <= 8, keep the old running
// max -> skip the fac LDS round-trip and the 16-wide acc rescale entirely.
// ---------------------------------------------------------------------------
__global__ __launch_bounds__(256) void attn_kernel(
    const unsigned short* __restrict__ Q, const unsigned short* __restrict__ K,
    const unsigned short* __restrict__ V, const int* __restrict__ adj,
    unsigned short* __restrict__ ctxh)
{
    __shared__ unsigned short K_lds[2][64][72];
    __shared__ unsigned short Vt_lds[2][64][72];  // transposed: [dv][k]
    __shared__ unsigned short P_lds[4][16][72];   // per-wave P tile [q][k]
    __shared__ float fac_lds[4][16];              // per-wave q -> factor bcast

    const int tid  = threadIdx.x;
    const int lane = tid & 63;
    const int w    = tid >> 6;
    const int l15  = lane & 15, lhi = lane >> 4;
    const int bh = blockIdx.y;
    const int b  = bh >> 3;
    const int hh = bh & 7;
    const int q0 = blockIdx.x * 64;

    const unsigned short* Qbh = Q + (size_t)bh * N_ * HD_;
    const unsigned short* Kbh = K + (size_t)bh * N_ * HD_;
    const unsigned short* Vbh = V + (size_t)bh * N_ * HD_;
    const int* adjb = adj + (size_t)b * N_ * N_;

    // Per-thread staging coordinates.
    const int sk  = tid & 63;          // K row within tile
    const int sc2 = tid >> 6;          // 0..3 (d-chunk)
    const int sv_k2  = (tid & 31) * 2; // V row pair
    const int sv_dvb = (tid >> 5) * 8; // V d-chunk

    // Q fragment: this lane's q-row for the softmax path is q0+w*16+l15.
    const int qrow = q0 + w * 16 + l15;
    bf16x8 aq0 = *(const bf16x8*)&Qbh[(size_t)qrow * HD_ + lhi * 8];
    bf16x8 aq1 = *(const bf16x8*)&Qbh[(size_t)qrow * HD_ + 32 + lhi * 8];

    const int qrow_base = q0 + w * 16 + lhi * 4;   // acc C-tile rows (PV output)

    f32x4 acc[4];
    #pragma unroll
    for (int t = 0; t < 4; ++t) acc[t] = (f32x4){0.f, 0.f, 0.f, 0.f};
    float m_q = -__builtin_inff();
    float l_q = 0.0f;
    const float NEG_INF = -__builtin_inff();
    const float scale = 0.125f;
    const float RESCALE_THR = 8.0f;

    // ---- Prologue: stage tile 0 into buffer 0.
    {
        u16x8 k0 = *(const u16x8*)&Kbh[(size_t)sk * HD_ + sc2 * 8];
        u16x8 k1 = *(const u16x8*)&Kbh[(size_t)sk * HD_ + (sc2 + 4) * 8];
        *(u16x8*)&K_lds[0][sk][sc2 * 8]       = k0;
        *(u16x8*)&K_lds[0][sk][(sc2 + 4) * 8] = k1;
        u16x8 v0 = *(const u16x8*)&Vbh[(size_t)sv_k2 * HD_ + sv_dvb];
        u16x8 v1 = *(const u16x8*)&Vbh[(size_t)(sv_k2 + 1) * HD_ + sv_dvb];
        #pragma unroll
        for (int i = 0; i < 8; ++i) {
            unsigned int pair = (unsigned int)(unsigned short)v0[i] |
                                ((unsigned int)(unsigned short)v1[i] << 16);
            *(unsigned int*)&Vt_lds[0][sv_dvb + i][sv_k2] = pair;
        }
    }
    i4 adjc[4], adjn[4];
    #pragma unroll
    for (int kt = 0; kt < 4; ++kt)
        adjc[kt] = *(const i4*)&adjb[(size_t)qrow * N_ + kt * 16 + lhi * 4];
    __syncthreads();

    int cur = 0;
    for (int kc = 0; kc < N_; kc += 64) {
        // ---- Issue next tile's loads (latency hides under this tile's compute).
        const int kcn = (kc + 64) & (N_ - 1);   // wraps on last iter (harmless)
        u16x8 nk0 = *(const u16x8*)&Kbh[(size_t)(kcn + sk) * HD_ + sc2 * 8];
        u16x8 nk1 = *(const u16x8*)&Kbh[(size_t)(kcn + sk) * HD_ + (sc2 + 4) * 8];
        u16x8 nv0 = *(const u16x8*)&Vbh[(size_t)(kcn + sv_k2) * HD_ + sv_dvb];
        u16x8 nv1 = *(const u16x8*)&Vbh[(size_t)(kcn + sv_k2 + 1) * HD_ + sv_dvb];
        #pragma unroll
        for (int kt = 0; kt < 4; ++kt)
            adjn[kt] = *(const i4*)&adjb[(size_t)qrow * N_ + kcn + kt * 16 + lhi * 4];

        // ---- S^T = K.Q^T on buf[cur]: D: q=l15, k=lhi*4+reg.
        f32x4 s[4];
        __builtin_amdgcn_s_setprio(1);
        #pragma unroll
        for (int kt = 0; kt < 4; ++kt) {
            bf16x8 bk0 = *(const bf16x8*)&K_lds[cur][kt * 16 + l15][lhi * 8];
            bf16x8 bk1 = *(const bf16x8*)&K_lds[cur][kt * 16 + l15][32 + lhi * 8];
            f32x4 z = {0.f, 0.f, 0.f, 0.f};
            z = __builtin_amdgcn_mfma_f32_16x16x32_bf16(bk0, aq0, z, 0, 0, 0);
            s[kt] = __builtin_amdgcn_mfma_f32_16x16x32_bf16(bk1, aq1, z, 0, 0, 0);
        }
        __builtin_amdgcn_s_setprio(0);

        // ---- In-register online softmax (one q-row per lane, 16 scores).
        float sm[16];
        #pragma unroll
        for (int kt = 0; kt < 4; ++kt)
            #pragma unroll
            for (int r = 0; r < 4; ++r)
                sm[kt * 4 + r] = adjc[kt][r] ? s[kt][r] * scale : NEG_INF;

        float mx = sm[0];
        #pragma unroll
        for (int i = 1; i < 16; ++i) mx = fmaxf(mx, sm[i]);
        mx = fmaxf(mx, __shfl_xor(mx, 16));
        mx = fmaxf(mx, __shfl_xor(mx, 32));

        // defer-max: skip rescale when no row in the wave grew its max by >THR.
        // (first tile: mx - (-inf) = +inf -> rescale; all-masked-forever row:
        //  NaN -> comparison false -> safe rescale path with NEG_INF guard.)
        const bool skip = __all(mx - m_q <= RESCALE_THR);

        float fac = 1.0f, p[16];
        if (skip) {
            #pragma unroll
            for (int i = 0; i < 16; ++i)
                p[i] = __expf(sm[i] - m_q);      // sm=-inf -> 0
        } else {
            const float mnew = fmaxf(m_q, mx);
            if (mnew == NEG_INF) {               // q-row fully masked so far
                #pragma unroll
                for (int i = 0; i < 16; ++i) p[i] = 0.0f;
            } else {
                fac = __expf(m_q - mnew);        // m_q = -inf -> 0
                #pragma unroll
                for (int i = 0; i < 16; ++i)
                    p[i] = __expf(sm[i] - mnew); // -inf -> 0
            }
            m_q = mnew;
            // Redistribute fac (per q=l15) to acc layout (q=lhi*4+r).
            if (lhi == 0) fac_lds[w][l15] = fac;
            f4 fac4 = *(const f4*)&fac_lds[w][lhi * 4];
            #pragma unroll
            for (int t = 0; t < 4; ++t)
                #pragma unroll
                for (int r = 0; r < 4; ++r)
                    acc[t][r] *= fac4[r];
        }

        float rs = 0.0f;
        #pragma unroll
        for (int i = 0; i < 16; ++i) rs += p[i];
        rs += __shfl_xor(rs, 16);
        rs += __shfl_xor(rs, 32);
        l_q = l_q * fac + rs;

        // ---- P -> bf16 -> P_lds[q][k] (wave-local).
        #pragma unroll
        for (int kt = 0; kt < 4; ++kt) {
            u16x4 pw;
            #pragma unroll
            for (int r = 0; r < 4; ++r) pw[r] = f2bf(p[kt * 4 + r]);
            *(u16x4*)&P_lds[w][l15][kt * 16 + lhi * 4] = pw;
        }

        // ---- ctx += P.V on buf[cur].
        #pragma unroll
        for (int ks = 0; ks < 2; ++ks) {
            bf16x8 ap = *(const bf16x8*)&P_lds[w][l15][ks * 32 + lhi * 8];
            __builtin_amdgcn_s_setprio(1);
            #pragma unroll
            for (int dvt = 0; dvt < 4; ++dvt) {
                bf16x8 bv = *(const bf16x8*)&Vt_lds[cur][dvt * 16 + l15][ks * 32 + lhi * 8];
                acc[dvt] = __builtin_amdgcn_mfma_f32_16x16x32_bf16(ap, bv, acc[dvt], 0, 0, 0);
            }
            __builtin_amdgcn_s_setprio(0);
        }

        // ---- Write staged regs into the other buffer, ONE barrier.
        const int nxt = cur ^ 1;
        *(u16x8*)&K_lds[nxt][sk][sc2 * 8]       = nk0;
        *(u16x8*)&K_lds[nxt][sk][(sc2 + 4) * 8] = nk1;
        #pragma unroll
        for (int i = 0; i < 8; ++i) {
            unsigned int pair = (unsigned int)(unsigned short)nv0[i] |
                                ((unsigned int)(unsigned short)nv1[i] << 16);
            *(unsigned int*)&Vt_lds[nxt][sv_dvb + i][sv_k2] = pair;
        }
        __syncthreads();
        cur = nxt;

        #pragma unroll
        for (int kt = 0; kt < 4; ++kt) adjc[kt] = adjn[kt];
    }

    // ---- Epilogue: redistribute final l, normalize, store bf16 ctx.
    if (lhi == 0) fac_lds[w][l15] = l_q;
    f4 lv = *(const f4*)&fac_lds[w][lhi * 4];
    #pragma unroll
    for (int r = 0; r < 4; ++r) {
        const int q = qrow_base + r;
        const float inv = (lv[r] > 0.0f) ? 1.0f / lv[r] : 0.0f;
        #pragma unroll
        for (int dvt = 0; dvt < 4; ++dvt)
            ctxh[((size_t)(b * N_ + q)) * D_ + hh * HD_ + dvt * 16 + l15] =
                f2bf(acc[dvt][r] * inv);
    }
}

// ---------------------------------------------------------------------------
// Residual + LayerNorm: out = LN(x + y1) * gamma + beta.  One wave per row.
// ---------------------------------------------------------------------------
__global__ __launch_bounds__(64) void ln_kernel(
    const float* __restrict__ x, const float* __restrict__ y1,
    const float* __restrict__ gamma, const float* __restrict__ beta,
    float* __restrict__ out)
{
    const int row = blockIdx.x;
    const int tid = threadIdx.x;
    const size_t base = (size_t)row * 512 + tid * 8;

    f4 v0 = *(const f4*)&x[base]     + *(const f4*)&y1[base];
    f4 v1 = *(const f4*)&x[base + 4] + *(const f4*)&y1[base + 4];

    float s = v0[0] + v0[1] + v0[2] + v0[3] + v1[0] + v1[1] + v1[2] + v1[3];
    #pragma unroll
    for (int off = 1; off < 64; off <<= 1) s += __shfl_xor(s, off);
    const float mu = s * (1.0f / 512.0f);

    float d2 = 0.0f;
    #pragma unroll
    for (int j = 0; j < 4; ++j) {
        const float a = v0[j] - mu, bq = v1[j] - mu;
        d2 += a * a + bq * bq;
    }
    #pragma unroll
    for (int off = 1; off < 64; off <<= 1) d2 += __shfl_xor(d2, off);
    const float rstd = rsqrtf(d2 * (1.0f / 512.0f) + 1e-5f);

    f4 g0 = *(const f4*)&gamma[tid * 8];
    f4 g1 = *(const f4*)&gamma[tid * 8 + 4];
    f4 be0 = *(const f4*)&beta[tid * 8];
    f4 be1 = *(const f4*)&beta[tid * 8 + 4];
    f4 o0, o1;
    #pragma unroll
    for (int j = 0; j < 4; ++j) {
        o0[j] = (v0[j] - mu) * rstd * g0[j] + be0[j];
        o1[j] = (v1[j] - mu) * rstd * g1[j] + be1[j];
    }
    *(f4*)&out[base]     = o0;
    *(f4*)&out[base + 4] = o1;
}

// ---------------------------------------------------------------------------
extern "C" void kernel_launch(void* const* d_in, const int* in_sizes, int n_in,
                              void* d_out, int out_size, void* d_ws, size_t ws_size,
                              hipStream_t stream)
{
    const float* x     = (const float*)d_in[0];
    const int*   adj   = (const int*)  d_in[1];
    const float* Wq    = (const float*)d_in[2];
    const float* bq    = (const float*)d_in[3];
    const float* Wk    = (const float*)d_in[4];
    const float* bk    = (const float*)d_in[5];
    const float* Wv    = (const float*)d_in[6];
    const float* bv    = (const float*)d_in[7];
    const float* Wo    = (const float*)d_in[8];
    const float* bo    = (const float*)d_in[9];
    const float* gamma = (const float*)d_in[10];
    const float* beta  = (const float*)d_in[11];
    float* out = (float*)d_out;

    const size_t elems = (size_t)B_ * N_ * D_;   // 2,097,152
    unsigned short* Qh   = (unsigned short*)d_ws;   // bf16 segments (4 MB each):
    unsigned short* Kh   = Qh + elems;
    unsigned short* Vh   = Kh + elems;
    unsigned short* ctxh = Vh + elems;
    float* y1 = (float*)Qh;    // overlay: Qh/Kh dead after attention

    // 1. QKV projections (bf16 MFMA; x and W converted inline during staging).
    qkv_mfma_kernel<<<dim3(4, 32, 3), 256, 0, stream>>>(
        x, Wq, Wk, Wv, bq, bk, bv, Qh, Kh, Vh);

    // 2. Masked flash attention (in-reg softmax + async dbuf + defer-max).
    attn_kernel<<<dim3(N_ / 64, B_ * H_), 256, 0, stream>>>(Qh, Kh, Vh, adj, ctxh);

    // 3. Output projection (bf16 MFMA, fp32 out; Wo converted inline).
    wo_mfma_kernel<<<dim3(4, 32), 256, 0, stream>>>(ctxh, Wo, bo, y1);

    // 4. Residual + LayerNorm.
    ln_kernel<<<B_ * N_, 64, 0, stream>>>(x, y1, gamma, beta, out);
}